// Round 3
// baseline (758.577 us; speedup 1.0000x reference)
//
#include <hip/hip_runtime.h>
#include <stdint.h>

#define LOG2_HASHMAP_SIZE 19
#define HASHMAP_SIZE (1u << LOG2_HASHMAP_SIZE)
#define HASHMAP_MASK (HASHMAP_SIZE - 1u)
#define N_LEVELS 4

typedef float f32x2 __attribute__((ext_vector_type(2)));

__device__ __forceinline__ float2 level_embed(const float* __restrict__ x,
                                              const float* __restrict__ tables,
                                              int i, int li, float r)
{
    const float px = x[3 * (size_t)i + 0];
    const float py = x[3 * (size_t)i + 1];
    const float pz = x[3 * (size_t)i + 2];

    const uint32_t P1 = 11614769u;
    const uint32_t P2 = 2654435761u;

    const float sx = px * r, sy = py * r, sz = pz * r;
    const float bx = floorf(sx), by = floorf(sy), bz = floorf(sz);
    const float tx = sx - bx, ty = sy - by, tz = sz - bz;
    const float ux = 1.0f - tx, uy = 1.0f - ty, uz = 1.0f - tz;

    const uint32_t ix = (uint32_t)(int)bx;
    const uint32_t iy = (uint32_t)(int)by;
    const uint32_t iz = (uint32_t)(int)bz;

    const uint32_t hx0 = ix,              hx1 = ix + 1u;
    const uint32_t hy0 = iy * P1,         hy1 = (iy + 1u) * P1;
    const uint32_t hz0 = iz * P2,         hz1 = (iz + 1u) * P2;

    const f32x2* __restrict__ tab =
        (const f32x2*)(tables + (size_t)li * HASHMAP_SIZE * 2);

    float f0 = 0.0f, f1 = 0.0f;
    // corner c: x-offset = (c>>2)&1, y-offset = (c>>1)&1, z-offset = c&1
    #pragma unroll
    for (int c = 0; c < 8; ++c) {
        const uint32_t h = (((c & 4) ? hx1 : hx0)
                          ^ ((c & 2) ? hy1 : hy0)
                          ^ ((c & 1) ? hz1 : hz0)) & HASHMAP_MASK;
        // Non-temporal: no L1 allocation -> avoid 64B line fill per 8B gather.
        const f32x2 e = __builtin_nontemporal_load(&tab[h]);
        const float w = ((c & 4) ? tx : ux)
                      * ((c & 2) ? ty : uy)
                      * ((c & 1) ? tz : uz);
        f0 += w * e.x;
        f1 += w * e.y;
    }
    return make_float2(f0, f1);
}

// Passes 0..2: write dense per-level float2 results into workspace.
__global__ __launch_bounds__(256) void pass_ws_kernel(
    const float* __restrict__ x, const float* __restrict__ tables,
    float2* __restrict__ ws, int li, float r, int n)
{
    const int i = blockIdx.x * blockDim.x + threadIdx.x;
    if (i >= n) return;
    ws[i] = level_embed(x, tables, i, li, r);
}

// Final pass: compute level 3, read ws levels 0..2, write [N,8] out.
__global__ __launch_bounds__(256) void final_kernel(
    const float* __restrict__ x, const float* __restrict__ tables,
    const float2* __restrict__ ws0, const float2* __restrict__ ws1,
    const float2* __restrict__ ws2, float* __restrict__ out, int n)
{
    const int i = blockIdx.x * blockDim.x + threadIdx.x;
    if (i >= n) return;
    const float2 e3 = level_embed(x, tables, i, 3, 512.0f);
    const float2 e0 = ws0[i];
    const float2 e1 = ws1[i];
    const float2 e2 = ws2[i];
    float4* op = (float4*)(out + 8 * (size_t)i);
    op[0] = make_float4(e0.x, e0.y, e1.x, e1.y);
    op[1] = make_float4(e2.x, e2.y, e3.x, e3.y);
}

// Fallback (ws too small): per-level pass writing strided into out directly.
__global__ __launch_bounds__(256) void pass_direct_kernel(
    const float* __restrict__ x, const float* __restrict__ tables,
    float* __restrict__ out, int li, float r, int n)
{
    const int i = blockIdx.x * blockDim.x + threadIdx.x;
    if (i >= n) return;
    const float2 e = level_embed(x, tables, i, li, r);
    float2* op = (float2*)(out + 8 * (size_t)i + 2 * li);
    *op = e;
}

extern "C" void kernel_launch(void* const* d_in, const int* in_sizes, int n_in,
                              void* d_out, int out_size, void* d_ws, size_t ws_size,
                              hipStream_t stream) {
    const float* x = (const float*)d_in[0];        // [N, 3]
    const float* tables = (const float*)d_in[1];   // [4, 2^19, 2]
    float* out = (float*)d_out;                    // [N, 8]
    const int n = in_sizes[0] / 3;

    const float res[N_LEVELS] = {30.0f, 80.0f, 210.0f, 512.0f};
    const int block = 256;
    const int grid = (n + block - 1) / block;

    const size_t ws_needed = 3 * (size_t)n * sizeof(float2);
    if (ws_size >= ws_needed) {
        float2* ws = (float2*)d_ws;
        for (int li = 0; li < 3; ++li) {
            pass_ws_kernel<<<grid, block, 0, stream>>>(
                x, tables, ws + (size_t)li * n, li, res[li], n);
        }
        final_kernel<<<grid, block, 0, stream>>>(
            x, tables, ws, ws + (size_t)n, ws + 2 * (size_t)n, out, n);
    } else {
        for (int li = 0; li < N_LEVELS; ++li) {
            pass_direct_kernel<<<grid, block, 0, stream>>>(
                x, tables, out, li, res[li], n);
        }
    }
}

// Round 4
// 347.650 us; speedup vs baseline: 2.1820x; 2.1820x over previous
//
#include <hip/hip_runtime.h>
#include <stdint.h>

#define LOG2_HASHMAP_SIZE 19
#define HASHMAP_SIZE (1u << LOG2_HASHMAP_SIZE)
#define HASHMAP_MASK (HASHMAP_SIZE - 1u)
#define N_LEVELS 4
#define TABLE_BYTES (HASHMAP_SIZE * 2u * 4u)   // 4 MiB per level

typedef unsigned int u32x2 __attribute__((ext_vector_type(2)));

#if __has_builtin(__builtin_amdgcn_make_buffer_rsrc) && __has_builtin(__builtin_amdgcn_raw_buffer_load_b64)
#define USE_BUFFER_SC0 1
#else
#define USE_BUFFER_SC0 0
#endif

__device__ __forceinline__ float2 level_embed(const float* __restrict__ x,
                                              const float* __restrict__ tables,
                                              int i, int li, float r)
{
    const float px = x[3 * (size_t)i + 0];
    const float py = x[3 * (size_t)i + 1];
    const float pz = x[3 * (size_t)i + 2];

    const uint32_t P1 = 11614769u;
    const uint32_t P2 = 2654435761u;

    const float sx = px * r, sy = py * r, sz = pz * r;
    const float bx = floorf(sx), by = floorf(sy), bz = floorf(sz);
    const float tx = sx - bx, ty = sy - by, tz = sz - bz;
    const float ux = 1.0f - tx, uy = 1.0f - ty, uz = 1.0f - tz;

    const uint32_t ix = (uint32_t)(int)bx;
    const uint32_t iy = (uint32_t)(int)by;
    const uint32_t iz = (uint32_t)(int)bz;

    const uint32_t hx0 = ix,              hx1 = ix + 1u;
    const uint32_t hy0 = iy * P1,         hy1 = (iy + 1u) * P1;
    const uint32_t hz0 = iz * P2,         hz1 = (iz + 1u) * P2;

    const float* tab = tables + (size_t)li * HASHMAP_SIZE * 2;

#if USE_BUFFER_SC0
    // Buffer descriptor over this level's 4 MiB table; word3 = raw untyped dword.
    __amdgpu_buffer_rsrc_t rsrc = __builtin_amdgcn_make_buffer_rsrc(
        (void*)tab, (short)0, (int)TABLE_BYTES, 0x00020000);
#endif

    float f0 = 0.0f, f1 = 0.0f;
    // corner c: x-offset = (c>>2)&1, y-offset = (c>>1)&1, z-offset = c&1
    #pragma unroll
    for (int c = 0; c < 8; ++c) {
        const uint32_t h = (((c & 4) ? hx1 : hx0)
                          ^ ((c & 2) ? hy1 : hy0)
                          ^ ((c & 1) ? hz1 : hz0)) & HASHMAP_MASK;
        float2 e;
#if USE_BUFFER_SC0
        // aux=1 -> sc0: no L1 allocation (no 64B line fill per 8B gather),
        // still allocates/hits L2. (nt would skip L2 too -- round-3 regression.)
        u32x2 d = __builtin_amdgcn_raw_buffer_load_b64(rsrc, (int)(h * 8u), 0, 1);
        __builtin_memcpy(&e, &d, 8);
#else
        e = ((const float2*)tab)[h];
#endif
        const float w = ((c & 4) ? tx : ux)
                      * ((c & 2) ? ty : uy)
                      * ((c & 1) ? tz : uz);
        f0 += w * e.x;
        f1 += w * e.y;
    }
    return make_float2(f0, f1);
}

// Passes 0..2: write dense per-level float2 results into workspace.
__global__ __launch_bounds__(256) void pass_ws_kernel(
    const float* __restrict__ x, const float* __restrict__ tables,
    float2* __restrict__ ws, int li, float r, int n)
{
    const int i = blockIdx.x * blockDim.x + threadIdx.x;
    if (i >= n) return;
    ws[i] = level_embed(x, tables, i, li, r);
}

// Final pass: compute level 3, read ws levels 0..2, write [N,8] out.
__global__ __launch_bounds__(256) void final_kernel(
    const float* __restrict__ x, const float* __restrict__ tables,
    const float2* __restrict__ ws0, const float2* __restrict__ ws1,
    const float2* __restrict__ ws2, float* __restrict__ out, int n)
{
    const int i = blockIdx.x * blockDim.x + threadIdx.x;
    if (i >= n) return;
    const float2 e3 = level_embed(x, tables, i, 3, 512.0f);
    const float2 e0 = ws0[i];
    const float2 e1 = ws1[i];
    const float2 e2 = ws2[i];
    float4* op = (float4*)(out + 8 * (size_t)i);
    op[0] = make_float4(e0.x, e0.y, e1.x, e1.y);
    op[1] = make_float4(e2.x, e2.y, e3.x, e3.y);
}

// Fallback (ws too small): per-level pass writing strided into out directly.
__global__ __launch_bounds__(256) void pass_direct_kernel(
    const float* __restrict__ x, const float* __restrict__ tables,
    float* __restrict__ out, int li, float r, int n)
{
    const int i = blockIdx.x * blockDim.x + threadIdx.x;
    if (i >= n) return;
    const float2 e = level_embed(x, tables, i, li, r);
    float2* op = (float2*)(out + 8 * (size_t)i + 2 * li);
    *op = e;
}

extern "C" void kernel_launch(void* const* d_in, const int* in_sizes, int n_in,
                              void* d_out, int out_size, void* d_ws, size_t ws_size,
                              hipStream_t stream) {
    const float* x = (const float*)d_in[0];        // [N, 3]
    const float* tables = (const float*)d_in[1];   // [4, 2^19, 2]
    float* out = (float*)d_out;                    // [N, 8]
    const int n = in_sizes[0] / 3;

    const float res[N_LEVELS] = {30.0f, 80.0f, 210.0f, 512.0f};
    const int block = 256;
    const int grid = (n + block - 1) / block;

    const size_t ws_needed = 3 * (size_t)n * sizeof(float2);
    if (ws_size >= ws_needed) {
        float2* ws = (float2*)d_ws;
        for (int li = 0; li < 3; ++li) {
            pass_ws_kernel<<<grid, block, 0, stream>>>(
                x, tables, ws + (size_t)li * n, li, res[li], n);
        }
        final_kernel<<<grid, block, 0, stream>>>(
            x, tables, ws, ws + (size_t)n, ws + 2 * (size_t)n, out, n);
    } else {
        for (int li = 0; li < N_LEVELS; ++li) {
            pass_direct_kernel<<<grid, block, 0, stream>>>(
                x, tables, out, li, res[li], n);
        }
    }
}